// Round 6
// baseline (384.965 us; speedup 1.0000x reference)
//
#include <hip/hip_runtime.h>
#include <hip/hip_bf16.h>
#include <math.h>

// Problem constants: B=4, T=2048, D=1024, H=16, DH=64
constexpr int Mdim = 8192;   // B*T
constexpr int Ndim = 1024;
constexpr int Kdim = 1024;
constexpr int Tseq = 2048;
constexpr int NH   = 16;

typedef __attribute__((ext_vector_type(8))) short short8;   // 8 bf16 = 4 VGPRs
typedef __attribute__((ext_vector_type(4))) float floatx4;  // MFMA C/D frag

__device__ __forceinline__ unsigned short f2b(float f) {   // RNE
  unsigned int x = __builtin_bit_cast(unsigned int, f);
  x += 0x7fffu + ((x >> 16) & 1u);
  return (unsigned short)(x >> 16);
}
// single-instruction packed f32->2xbf16 (lo=a, hi=b), RNE
__device__ __forceinline__ unsigned int cvtpk(float a, float b) {
  unsigned int r;
  asm("v_cvt_pk_bf16_f32 %0, %1, %2" : "=v"(r) : "v"(a), "v"(b));
  return r;
}
__device__ __forceinline__ float max3f(float a, float b, float c) {
  float d;
  asm("v_max3_f32 %0, %1, %2, %3" : "=v"(d) : "v"(a), "v"(b), "v"(c));
  return d;
}
// async global->LDS, 16B per lane; LDS dest = uniform base + lane*16
__device__ __forceinline__ void gld16(const void* g, const void* l) {
  __builtin_amdgcn_global_load_lds(
      (const __attribute__((address_space(1))) unsigned int*)(unsigned long long)g,
      (__attribute__((address_space(3))) unsigned int*)(unsigned int)(unsigned long long)l,
      16, 0, 0);
}
// Raw barrier without waitcnt drain (sched_barrier pins program order only).
__device__ __forceinline__ void barrier_raw() {
  __builtin_amdgcn_sched_barrier(0);
  __builtin_amdgcn_s_barrier();
  __builtin_amdgcn_sched_barrier(0);
}

// ---------------------------------------------------------------- casts
__global__ __launch_bounds__(256) void cast_k(
    const float* __restrict__ q, const float* __restrict__ k,
    const float* __restrict__ v, const float* __restrict__ wq,
    const float* __restrict__ wk, const float* __restrict__ wv,
    const float* __restrict__ wo,
    unsigned short* d0, unsigned short* d1, unsigned short* d2,
    unsigned short* d3, unsigned short* d4, unsigned short* d5,
    unsigned short* d6) {
  int y = blockIdx.y;
  const float* s = y == 0 ? q : y == 1 ? k : y == 2 ? v
                 : y == 3 ? wq : y == 4 ? wk : y == 5 ? wv : wo;
  unsigned short* d = y == 0 ? d0 : y == 1 ? d1 : y == 2 ? d2
                    : y == 3 ? d3 : y == 4 ? d4 : y == 5 ? d5 : d6;
  size_t n = (y < 3) ? (size_t)Mdim * Kdim : (size_t)Ndim * Kdim;
  size_t i = ((size_t)blockIdx.x * 256 + threadIdx.x) * 8;
  if (i >= n) return;
  float4 a = *(const float4*)(s + i);
  float4 b = *(const float4*)(s + i + 4);
  uint4 w;
  w.x = (unsigned)f2b(a.x) | ((unsigned)f2b(a.y) << 16);
  w.y = (unsigned)f2b(a.z) | ((unsigned)f2b(a.w) << 16);
  w.z = (unsigned)f2b(b.x) | ((unsigned)f2b(b.y) << 16);
  w.w = (unsigned)f2b(b.z) | ((unsigned)f2b(b.w) << 16);
  *(uint4*)(d + i) = w;
}

// ---------------------------------------------------------------- QKV GEMM
// 128x128 / BK=64 / 4-wave 2-phase (m97-family; multi-block overlap) with
// bijective XCD-chunked swizzle over the full 1536-block grid and
// __launch_bounds__(256,4).  (unchanged this round)
__launch_bounds__(256, 4)
__global__ void gemm_qkv(const unsigned short* __restrict__ Aq,
                         const unsigned short* __restrict__ Ak,
                         const unsigned short* __restrict__ Av,
                         const unsigned short* __restrict__ Wq,
                         const unsigned short* __restrict__ Wk,
                         const unsigned short* __restrict__ Wv,
                         unsigned short* __restrict__ Qh,
                         unsigned short* __restrict__ Kh,
                         float* __restrict__ Kout,
                         unsigned short* __restrict__ VTg,
                         float* __restrict__ Vout) {
  __shared__ __align__(16) unsigned short As[128 * 64];
  __shared__ __align__(16) unsigned short Bs[128 * 64];

  // bijective XCD-chunked swizzle: nwg = 8*64*3 = 1536, 1536%8==0, chunk 192.
  const int flat = (blockIdx.z * 64 + blockIdx.y) * 8 + blockIdx.x;
  const int wgid = (flat & 7) * 192 + (flat >> 3);
  const int z    = wgid >> 9;            // 512 tiles per z-plane
  const int rem  = wgid & 511;
  const int m0   = (rem >> 3) * 128;     // 64 m-tiles
  const int n0   = (rem & 7) * 128;      // 8 n-tiles (innermost: A-panel reuse)

  const unsigned short* __restrict__ A = z == 0 ? Aq : z == 1 ? Ak : Av;
  const unsigned short* __restrict__ W = z == 0 ? Wq : z == 1 ? Wk : Wv;

  const int tid  = threadIdx.x;
  const int lane = tid & 63;
  const int wave = tid >> 6;
  const int l15  = lane & 15;
  const int quad = lane >> 4;
  const int sw   = l15 & 7;
  const int wm = (wave >> 1) * 64;
  const int wn = (wave & 1) * 64;

  floatx4 acc[4][4];
  for (int i = 0; i < 4; i++)
    for (int j = 0; j < 4; j++) acc[i][j] = (floatx4)0.0f;

  const int srow8 = lane >> 3;   // staging: 8 lanes per 64-col row
  const int sg    = lane & 7;

  for (int kt = 0; kt < Kdim; kt += 64) {
    for (int jj = 0; jj < 4; jj++) {
      int cc = wave * 4 + jj;            // 1KB chunk = 8 rows
      int row = cc * 8 + srow8;
      int G = sg ^ (row & 7);
      gld16(A + (size_t)(m0 + row) * Kdim + kt + G * 8, As + cc * 512);
      gld16(W + (size_t)(n0 + row) * Kdim + kt + G * 8, Bs + cc * 512);
    }
    __syncthreads();

    for (int hf = 0; hf < 2; hf++) {
      short8 af[4], bw[4];
      for (int mi = 0; mi < 4; mi++)
        af[mi] = *(const short8*)(As + (wm + mi * 16 + l15) * 64 +
                                  (((hf * 4 + quad) ^ sw) << 3));
      for (int ni = 0; ni < 4; ni++)
        bw[ni] = *(const short8*)(Bs + (wn + ni * 16 + l15) * 64 +
                                  (((hf * 4 + quad) ^ sw) << 3));
      for (int mi = 0; mi < 4; mi++)
        for (int ni = 0; ni < 4; ni++)
          acc[mi][ni] = __builtin_amdgcn_mfma_f32_16x16x32_bf16(
              bw[ni], af[mi], acc[mi][ni], 0, 0, 0);   // swapped: C^T
    }
    __syncthreads();
  }

  // Epilogue. C^T: lane row (quad*4+r) = n (dh), lane col (l15) = m (t).
  const int gm = m0 + wm + l15;              // t-row base for mi=0 (+16 per mi)
  for (int mi = 0; mi < 4; mi++) {
    int t_abs = gm + mi * 16;
    int b = t_abs >> 11, tb = t_abs & (Tseq - 1);
    for (int ni = 0; ni < 4; ni++) {
      int gn0 = n0 + wn + ni * 16 + quad * 4;
      int h = gn0 >> 6, dh0 = gn0 & 63;
      size_t base = ((size_t)((b * NH + h) * Tseq + tb)) * 64 + dh0;
      floatx4 v = acc[mi][ni];
      if (z == 0) {
        ushort4 w = {f2b(v[0]), f2b(v[1]), f2b(v[2]), f2b(v[3])};
        *(ushort4*)(Qh + base) = w;
      } else if (z == 1) {
        *(float4*)(Kout + base) = *(float4*)&v;
        ushort4 w = {f2b(v[0]), f2b(v[1]), f2b(v[2]), f2b(v[3])};
        *(ushort4*)(Kh + base) = w;
      } else {
        *(float4*)(Vout + base) = *(float4*)&v;
        size_t vtb = ((size_t)((b * NH + h) * 64 + dh0)) * Tseq + tb;
        for (int r = 0; r < 4; r++)
          VTg[vtb + (size_t)r * Tseq] = f2b(v[r]);   // 16-lane 32B segments
      }
    }
  }
}

// ---------------------------------------------------------------- O GEMM
// 64x128 tile: 1024 blocks @ 24KB LDS -> 6 blocks/CU, + bijective
// XCD-chunked swizzle (n-inner: A-panel L2 reuse).  (as round 5)
__launch_bounds__(256, 6)
__global__ void gemm_o(const unsigned short* __restrict__ A,
                       const unsigned short* __restrict__ W,
                       float* __restrict__ Cf) {
  __shared__ __align__(16) unsigned short As[64 * 64];    // 8KB
  __shared__ __align__(16) unsigned short Bs[128 * 64];   // 16KB

  // bijective XCD-chunked swizzle: nwg = 8*128 = 1024, chunk 128.
  const int flat = blockIdx.y * 8 + blockIdx.x;
  const int wgid = (flat & 7) * 128 + (flat >> 3);
  const int m0   = (wgid >> 3) * 64;     // 128 m-tiles
  const int n0   = (wgid & 7) * 128;     // 8 n-tiles (innermost: A reuse)

  const int tid  = threadIdx.x;
  const int lane = tid & 63;
  const int wave = tid >> 6;
  const int l15  = lane & 15;
  const int quad = lane >> 4;
  const int sw   = l15 & 7;
  const int wm = (wave >> 1) * 32;       // 2 m-halves of 32
  const int wn = (wave & 1) * 64;        // 2 n-halves of 64

  floatx4 acc[2][4];
  for (int i = 0; i < 2; i++)
    for (int j = 0; j < 4; j++) acc[i][j] = (floatx4)0.0f;

  const int srow8 = lane >> 3;
  const int sg    = lane & 7;

  for (int kt = 0; kt < Kdim; kt += 64) {
    for (int jj = 0; jj < 2; jj++) {     // A: 64 rows = 8 chunks
      int cc = wave * 2 + jj;
      int row = cc * 8 + srow8;
      int G = sg ^ (row & 7);
      gld16(A + (size_t)(m0 + row) * Kdim + kt + G * 8, As + cc * 512);
    }
    for (int jj = 0; jj < 4; jj++) {     // B: 128 rows = 16 chunks
      int cc = wave * 4 + jj;
      int row = cc * 8 + srow8;
      int G = sg ^ (row & 7);
      gld16(W + (size_t)(n0 + row) * Kdim + kt + G * 8, Bs + cc * 512);
    }
    __syncthreads();

    for (int hf = 0; hf < 2; hf++) {
      short8 af[2], bw[4];
      for (int mi = 0; mi < 2; mi++)
        af[mi] = *(const short8*)(As + (wm + mi * 16 + l15) * 64 +
                                  (((hf * 4 + quad) ^ sw) << 3));
      for (int ni = 0; ni < 4; ni++)
        bw[ni] = *(const short8*)(Bs + (wn + ni * 16 + l15) * 64 +
                                  (((hf * 4 + quad) ^ sw) << 3));
      for (int mi = 0; mi < 2; mi++)
        for (int ni = 0; ni < 4; ni++)
          acc[mi][ni] = __builtin_amdgcn_mfma_f32_16x16x32_bf16(
              bw[ni], af[mi], acc[mi][ni], 0, 0, 0);   // swapped: C^T
    }
    __syncthreads();
  }

  for (int mi = 0; mi < 2; mi++) {
    int t_abs = m0 + wm + mi * 16 + l15;
    for (int ni = 0; ni < 4; ni++) {
      int gn0 = n0 + wn + ni * 16 + quad * 4;
      floatx4 v = acc[mi][ni];
      *(float4*)(Cf + (size_t)t_abs * Ndim + gn0) = *(float4*)&v;
    }
  }
}

// ---------------------------------------------------------------- attention
// Causal flash attention, S^T formulation. One 64-row q-tile per block
// (2048 blocks, longest-first). LDS 32KB (K dbuf 16K + V single 8K + P 8K)
// -> 5 blocks/CU. V(t) staged at iter top (latency hides under QK^T+softmax);
// counted vmcnt(2) keeps K(t+1) in flight.
// ROUND 6 FIX: V is staged and consumed in the SAME iteration, and PV reads
// all 64 rows (staged by ALL waves) — a per-wave vmcnt only covers this
// wave's rows. A workgroup barrier AFTER the vmcnt and BEFORE PV publishes
// every wave's V writes (each wave arrives only after its own loads landed).
// Round 5 lacked this barrier -> cross-wave race -> NaN.
__launch_bounds__(256, 5)
__global__ void attn_k(const unsigned short* __restrict__ Qh,
                       const unsigned short* __restrict__ Kh,
                       const unsigned short* __restrict__ VTg,
                       unsigned short* __restrict__ Og) {
  __shared__ __align__(16) unsigned short Kt[2][64 * 64];
  __shared__ __align__(16) unsigned short Vt[64 * 64];
  __shared__ __align__(16) unsigned short Pl[64 * 64];

  const int tid  = threadIdx.x;
  const int lane = tid & 63;
  const int wave = tid >> 6;
  const int l15  = lane & 15;
  const int quad = lane >> 4;
  const int sw   = l15 & 7;
  const int bh   = blockIdx.x;
  const int a    = 31 - (int)blockIdx.y;   // longest blocks dispatch first
  const int nkt  = a + 1;

  const size_t headoff = (size_t)bh * Tseq * 64;
  const int srow8 = lane >> 3;
  const int sg    = lane & 7;
  const float kscale = 0.18033688011112042f;  // (1/8) * log2(e)
  const int b = bh >> 4, h = bh & 15;
  const int qg = a * 64 + wave * 16 + l15;    // this lane's q row

  short8 bq[2];
#pragma unroll
  for (int hf = 0; hf < 2; hf++)
    bq[hf] = *(const short8*)(Qh + headoff + (size_t)qg * 64 +
                              hf * 32 + quad * 8);

  floatx4 o[4];
#pragma unroll
  for (int nb = 0; nb < 4; nb++) o[nb] = (floatx4)0.0f;
  float mrow = -INFINITY, lrow = 0.0f;

  auto stageK = [&](int par, int kt) {
    const int k0 = kt * 64;
#pragma unroll
    for (int jj = 0; jj < 2; jj++) {
      int cc  = wave * 2 + jj;
      int row = cc * 8 + srow8;
      int G   = sg ^ (row & 7);
      gld16(Kh + headoff + (size_t)(k0 + row) * 64 + G * 8, &Kt[par][cc * 512]);
    }
  };
  auto stageV = [&](int kt) {
    const int k0 = kt * 64;
#pragma unroll
    for (int jj = 0; jj < 2; jj++) {
      int cc  = wave * 2 + jj;
      int row = cc * 8 + srow8;
      int G   = sg ^ (row & 7);
      gld16(VTg + ((size_t)bh * 64 + row) * Tseq + k0 + G * 8, Vt + cc * 512);
    }
  };

  stageK(0, 0);
  __builtin_amdgcn_sched_barrier(0);
  asm volatile("s_waitcnt vmcnt(0)");
  barrier_raw();

  for (int kt = 0; kt < nkt; kt++) {
    const int par = kt & 1;
    const int k0 = kt * 64;
    // V(t) first, then K(t+1): before PV, vmcnt(2) waits V only.
    stageV(kt);
    const bool pre = (kt + 1 < nkt);
    if (pre) stageK(par ^ 1, kt + 1);
    __builtin_amdgcn_sched_barrier(0);

    // QK^T (S^T frag: lane l15 = q-row, quad*4+r (+16nb) = k)
    floatx4 st[4];
#pragma unroll
    for (int nb = 0; nb < 4; nb++) {
      const unsigned short* kr = &Kt[par][(nb * 16 + l15) * 64];
      short8 ak0 = *(const short8*)(kr + ((quad ^ sw) << 3));
      short8 ak1 = *(const short8*)(kr + (((quad + 4) ^ sw) << 3));
      floatx4 acc0 = (floatx4)0.0f;
      acc0 = __builtin_amdgcn_mfma_f32_16x16x32_bf16(ak0, bq[0], acc0, 0, 0, 0);
      acc0 = __builtin_amdgcn_mfma_f32_16x16x32_bf16(ak1, bq[1], acc0, 0, 0, 0);
      st[nb] = acc0;
    }

    if (kt == nkt - 1) {   // only the diagonal tile needs masking
#pragma unroll
      for (int nb = 0; nb < 4; nb++)
#pragma unroll
        for (int r = 0; r < 4; r++) {
          int kg = k0 + nb * 16 + quad * 4 + r;
          if (kg > qg) st[nb][r] = -INFINITY;
        }
    }

    // row max: v_max3 tree (16 -> 8 ops) + cross-quad shfl
    float m0_ = max3f(st[0][0], st[0][1], st[0][2]);
    float m1_ = max3f(st[0][3], st[1][0], st[1][1]);
    float m2_ = max3f(st[1][2], st[1][3], st[2][0]);
    float m3_ = max3f(st[2][1], st[2][2], st[2][3]);
    float m4_ = max3f(st[3][0], st[3][1], st[3][2]);
    float mt = fmaxf(max3f(m0_, m1_, m2_), max3f(m3_, m4_, st[3][3]));
    mt = fmaxf(mt, __shfl_xor(mt, 16, 64));
    mt = fmaxf(mt, __shfl_xor(mt, 32, 64));

    // T13 defer-max: skip rescale while growth <= 8 log2-units (P <= 2^8)
    if (!__all((mt - mrow) * kscale <= 8.0f)) {
      float mnew = fmaxf(mrow, mt);
      float al = __builtin_amdgcn_exp2f((mrow - mnew) * kscale);
      mrow = mnew;
      lrow *= al;
#pragma unroll
      for (int nb = 0; nb < 4; nb++)
#pragma unroll
        for (int r = 0; r < 4; r++) o[nb][r] *= al;
    }
    const float ms = mrow * kscale;

    float rs = 0.0f;
    const int prow = (wave * 16 + l15) * 64;
#pragma unroll
    for (int nb = 0; nb < 4; nb++) {
      float p0 = __builtin_amdgcn_exp2f(__builtin_fmaf(st[nb][0], kscale, -ms));
      float p1 = __builtin_amdgcn_exp2f(__builtin_fmaf(st[nb][1], kscale, -ms));
      float p2 = __builtin_amdgcn_exp2f(__builtin_fmaf(st[nb][2], kscale, -ms));
      float p3 = __builtin_amdgcn_exp2f(__builtin_fmaf(st[nb][3], kscale, -ms));
      rs += (p0 + p1) + (p2 + p3);
      uint2 w = {cvtpk(p0, p1), cvtpk(p2, p3)};
      int klb = nb * 16 + quad * 4;
      int colp = (((klb >> 3) ^ sw) << 3) | (klb & 7);
      *(uint2*)(Pl + prow + colp) = w;
    }
    rs += __shfl_xor(rs, 16, 64);
    rs += __shfl_xor(rs, 32, 64);
    lrow += rs;

    // wait own V(t) loads (K(t+1) stays in flight), then BARRIER to publish
    // every wave's V rows before PV reads the full tile (round-6 fix).
    __builtin_amdgcn_sched_barrier(0);
    if (pre) asm volatile("s_waitcnt vmcnt(2)");
    else     asm volatile("s_waitcnt vmcnt(0)");
    barrier_raw();

    // PV
    short8 av[4][2];
#pragma unroll
    for (int nb = 0; nb < 4; nb++) {
      const unsigned short* vr = Vt + (nb * 16 + l15) * 64;
      av[nb][0] = *(const short8*)(vr + ((quad ^ sw) << 3));
      av[nb][1] = *(const short8*)(vr + (((quad + 4) ^ sw) << 3));
    }
    const unsigned short* pr = Pl + prow;
    short8 bp0 = *(const short8*)(pr + ((quad ^ sw) << 3));
    short8 bp1 = *(const short8*)(pr + (((quad + 4) ^ sw) << 3));
#pragma unroll
    for (int nb = 0; nb < 4; nb++) {
      o[nb] = __builtin_amdgcn_mfma_f32_16x16x32_bf16(av[nb][0], bp0, o[nb], 0, 0, 0);
      o[nb] = __builtin_amdgcn_mfma_f32_16x16x32_bf16(av[nb][1], bp1, o[nb], 0, 0, 0);
    }

    // drain K(t+1) (long since issued); barrier frees Vt/Pl for next iter
    __builtin_amdgcn_sched_barrier(0);
    asm volatile("s_waitcnt vmcnt(0)");
    barrier_raw();
  }

  float inv = 1.0f / lrow;
  size_t rowoff = ((size_t)(b * Tseq + qg)) * 1024 + h * 64;
#pragma unroll
  for (int nb = 0; nb < 4; nb++) {
    ushort4 w;
    w.x = f2b(o[nb][0] * inv);
    w.y = f2b(o[nb][1] * inv);
    w.z = f2b(o[nb][2] * inv);
    w.w = f2b(o[nb][3] * inv);
    *(ushort4*)(Og + rowoff + nb * 16 + quad * 4) = w;
  }
}

// ---------------------------------------------------------------- launcher
extern "C" void kernel_launch(void* const* d_in, const int* in_sizes, int n_in,
                              void* d_out, int out_size, void* d_ws, size_t ws_size,
                              hipStream_t stream) {
  const float* q  = (const float*)d_in[0];
  const float* k  = (const float*)d_in[1];
  const float* v  = (const float*)d_in[2];
  const float* wq = (const float*)d_in[3];
  const float* wk = (const float*)d_in[4];
  const float* wv = (const float*)d_in[5];
  const float* wo = (const float*)d_in[6];
  // d_in[7] = attn_mask: deterministically causal; handled analytically.
  float* out = (float*)d_out;

  constexpr size_t BTD = (size_t)Mdim * Kdim;
  constexpr size_t DD  = (size_t)Ndim * Kdim;
  constexpr size_t MB16 = BTD * 2;

  char* ws = (char*)d_ws;
  unsigned short* Qh  = (unsigned short*)(ws);
  unsigned short* Kh  = (unsigned short*)(ws + MB16);
  unsigned short* VTg = (unsigned short*)(ws + 2 * MB16);
  unsigned short* Og  = (unsigned short*)(ws + 3 * MB16);
  unsigned short* qb  = (unsigned short*)(ws + 4 * MB16);
  unsigned short* kb  = (unsigned short*)(ws + 5 * MB16);
  unsigned short* vb  = (unsigned short*)(ws + 6 * MB16);
  unsigned short* wqb = (unsigned short*)(ws + 7 * MB16);
  unsigned short* wkb = wqb + DD;
  unsigned short* wvb = wkb + DD;
  unsigned short* wob = wvb + DD;

  float* Kout = out + BTD;
  float* Vout = out + 2 * BTD;

  cast_k<<<dim3(4096, 7), 256, 0, stream>>>(q, k, v, wq, wk, wv, wo,
                                            qb, kb, vb, wqb, wkb, wvb, wob);

  gemm_qkv<<<dim3(8, 64, 3), 256, 0, stream>>>(
      qb, kb, vb, wqb, wkb, wvb, Qh, Kh, Kout, VTg, Vout);

  attn_k<<<dim3(4 * NH, 32), 256, 0, stream>>>(Qh, Kh, VTg, Og);

  gemm_o<<<dim3(8, Mdim / 64), 256, 0, stream>>>(Og, wob, out);
}

// Round 8
// 347.901 us; speedup vs baseline: 1.1065x; 1.1065x over previous
//
#include <hip/hip_runtime.h>
#include <hip/hip_bf16.h>
#include <math.h>

// Problem constants: B=4, T=2048, D=1024, H=16, DH=64
constexpr int Mdim = 8192;   // B*T
constexpr int Ndim = 1024;
constexpr int Kdim = 1024;
constexpr int Tseq = 2048;
constexpr int NH   = 16;

typedef __attribute__((ext_vector_type(8))) short short8;   // 8 bf16 = 4 VGPRs
typedef __attribute__((ext_vector_type(4))) float floatx4;  // MFMA C/D frag

__device__ __forceinline__ unsigned short f2b(float f) {   // RNE
  unsigned int x = __builtin_bit_cast(unsigned int, f);
  x += 0x7fffu + ((x >> 16) & 1u);
  return (unsigned short)(x >> 16);
}
// single-instruction packed f32->2xbf16 (lo=a, hi=b), RNE
__device__ __forceinline__ unsigned int cvtpk(float a, float b) {
  unsigned int r;
  asm("v_cvt_pk_bf16_f32 %0, %1, %2" : "=v"(r) : "v"(a), "v"(b));
  return r;
}
__device__ __forceinline__ float max3f(float a, float b, float c) {
  float d;
  asm("v_max3_f32 %0, %1, %2, %3" : "=v"(d) : "v"(a), "v"(b), "v"(c));
  return d;
}
// async global->LDS, 16B per lane; LDS dest = uniform base + lane*16
__device__ __forceinline__ void gld16(const void* g, const void* l) {
  __builtin_amdgcn_global_load_lds(
      (const __attribute__((address_space(1))) unsigned int*)(unsigned long long)g,
      (__attribute__((address_space(3))) unsigned int*)(unsigned int)(unsigned long long)l,
      16, 0, 0);
}
// Raw barrier without waitcnt drain (sched_barrier pins program order only).
__device__ __forceinline__ void barrier_raw() {
  __builtin_amdgcn_sched_barrier(0);
  __builtin_amdgcn_s_barrier();
  __builtin_amdgcn_sched_barrier(0);
}

// ---------------------------------------------------------------- casts
__global__ __launch_bounds__(256) void cast_k(
    const float* __restrict__ q, const float* __restrict__ k,
    const float* __restrict__ v, const float* __restrict__ wq,
    const float* __restrict__ wk, const float* __restrict__ wv,
    const float* __restrict__ wo,
    unsigned short* d0, unsigned short* d1, unsigned short* d2,
    unsigned short* d3, unsigned short* d4, unsigned short* d5,
    unsigned short* d6) {
  int y = blockIdx.y;
  const float* s = y == 0 ? q : y == 1 ? k : y == 2 ? v
                 : y == 3 ? wq : y == 4 ? wk : y == 5 ? wv : wo;
  unsigned short* d = y == 0 ? d0 : y == 1 ? d1 : y == 2 ? d2
                    : y == 3 ? d3 : y == 4 ? d4 : y == 5 ? d5 : d6;
  size_t n = (y < 3) ? (size_t)Mdim * Kdim : (size_t)Ndim * Kdim;
  size_t i = ((size_t)blockIdx.x * 256 + threadIdx.x) * 8;
  if (i >= n) return;
  float4 a = *(const float4*)(s + i);
  float4 b = *(const float4*)(s + i + 4);
  uint4 w;
  w.x = (unsigned)f2b(a.x) | ((unsigned)f2b(a.y) << 16);
  w.y = (unsigned)f2b(a.z) | ((unsigned)f2b(a.w) << 16);
  w.z = (unsigned)f2b(b.x) | ((unsigned)f2b(b.y) << 16);
  w.w = (unsigned)f2b(b.z) | ((unsigned)f2b(b.w) << 16);
  *(uint4*)(d + i) = w;
}

// ---------------------------------------------------------------- QKV GEMM
// 128x128 / BK=64 / 4-wave 2-phase (m97-family; multi-block overlap) with
// bijective XCD-chunked swizzle over the full 1536-block grid and
// __launch_bounds__(256,4).  (unchanged)
__launch_bounds__(256, 4)
__global__ void gemm_qkv(const unsigned short* __restrict__ Aq,
                         const unsigned short* __restrict__ Ak,
                         const unsigned short* __restrict__ Av,
                         const unsigned short* __restrict__ Wq,
                         const unsigned short* __restrict__ Wk,
                         const unsigned short* __restrict__ Wv,
                         unsigned short* __restrict__ Qh,
                         unsigned short* __restrict__ Kh,
                         float* __restrict__ Kout,
                         unsigned short* __restrict__ VTg,
                         float* __restrict__ Vout) {
  __shared__ __align__(16) unsigned short As[128 * 64];
  __shared__ __align__(16) unsigned short Bs[128 * 64];

  // bijective XCD-chunked swizzle: nwg = 8*64*3 = 1536, 1536%8==0, chunk 192.
  const int flat = (blockIdx.z * 64 + blockIdx.y) * 8 + blockIdx.x;
  const int wgid = (flat & 7) * 192 + (flat >> 3);
  const int z    = wgid >> 9;            // 512 tiles per z-plane
  const int rem  = wgid & 511;
  const int m0   = (rem >> 3) * 128;     // 64 m-tiles
  const int n0   = (rem & 7) * 128;      // 8 n-tiles (innermost: A-panel reuse)

  const unsigned short* __restrict__ A = z == 0 ? Aq : z == 1 ? Ak : Av;
  const unsigned short* __restrict__ W = z == 0 ? Wq : z == 1 ? Wk : Wv;

  const int tid  = threadIdx.x;
  const int lane = tid & 63;
  const int wave = tid >> 6;
  const int l15  = lane & 15;
  const int quad = lane >> 4;
  const int sw   = l15 & 7;
  const int wm = (wave >> 1) * 64;
  const int wn = (wave & 1) * 64;

  floatx4 acc[4][4];
  for (int i = 0; i < 4; i++)
    for (int j = 0; j < 4; j++) acc[i][j] = (floatx4)0.0f;

  const int srow8 = lane >> 3;   // staging: 8 lanes per 64-col row
  const int sg    = lane & 7;

  for (int kt = 0; kt < Kdim; kt += 64) {
    for (int jj = 0; jj < 4; jj++) {
      int cc = wave * 4 + jj;            // 1KB chunk = 8 rows
      int row = cc * 8 + srow8;
      int G = sg ^ (row & 7);
      gld16(A + (size_t)(m0 + row) * Kdim + kt + G * 8, As + cc * 512);
      gld16(W + (size_t)(n0 + row) * Kdim + kt + G * 8, Bs + cc * 512);
    }
    __syncthreads();

    for (int hf = 0; hf < 2; hf++) {
      short8 af[4], bw[4];
      for (int mi = 0; mi < 4; mi++)
        af[mi] = *(const short8*)(As + (wm + mi * 16 + l15) * 64 +
                                  (((hf * 4 + quad) ^ sw) << 3));
      for (int ni = 0; ni < 4; ni++)
        bw[ni] = *(const short8*)(Bs + (wn + ni * 16 + l15) * 64 +
                                  (((hf * 4 + quad) ^ sw) << 3));
      for (int mi = 0; mi < 4; mi++)
        for (int ni = 0; ni < 4; ni++)
          acc[mi][ni] = __builtin_amdgcn_mfma_f32_16x16x32_bf16(
              bw[ni], af[mi], acc[mi][ni], 0, 0, 0);   // swapped: C^T
    }
    __syncthreads();
  }

  // Epilogue. C^T: lane row (quad*4+r) = n (dh), lane col (l15) = m (t).
  const int gm = m0 + wm + l15;              // t-row base for mi=0 (+16 per mi)
  for (int mi = 0; mi < 4; mi++) {
    int t_abs = gm + mi * 16;
    int b = t_abs >> 11, tb = t_abs & (Tseq - 1);
    for (int ni = 0; ni < 4; ni++) {
      int gn0 = n0 + wn + ni * 16 + quad * 4;
      int h = gn0 >> 6, dh0 = gn0 & 63;
      size_t base = ((size_t)((b * NH + h) * Tseq + tb)) * 64 + dh0;
      floatx4 v = acc[mi][ni];
      if (z == 0) {
        ushort4 w = {f2b(v[0]), f2b(v[1]), f2b(v[2]), f2b(v[3])};
        *(ushort4*)(Qh + base) = w;
      } else if (z == 1) {
        *(float4*)(Kout + base) = *(float4*)&v;
        ushort4 w = {f2b(v[0]), f2b(v[1]), f2b(v[2]), f2b(v[3])};
        *(ushort4*)(Kh + base) = w;
      } else {
        *(float4*)(Vout + base) = *(float4*)&v;
        size_t vtb = ((size_t)((b * NH + h) * 64 + dh0)) * Tseq + tb;
        for (int r = 0; r < 4; r++)
          VTg[vtb + (size_t)r * Tseq] = f2b(v[r]);   // 16-lane 32B segments
      }
    }
  }
}

// ---------------------------------------------------------------- O GEMM
// REVERT of round-5's 64x128 retile (isolated as the +19us regressor:
// per-output staging cost x1.33, Wo re-read x2). Known-good 128x128 / BK=64
// body + the two levers verified on gemm_qkv in R4: bijective XCD-chunked
// swizzle (nwg=512, chunk 64, n-inner -> A-panel read once then 7x L2 hits)
// and __launch_bounds__(256,4).
__launch_bounds__(256, 4)
__global__ void gemm_o(const unsigned short* __restrict__ A,
                       const unsigned short* __restrict__ W,
                       float* __restrict__ Cf) {
  __shared__ __align__(16) unsigned short As[128 * 64];
  __shared__ __align__(16) unsigned short Bs[128 * 64];

  // bijective XCD-chunked swizzle: nwg = 8*64 = 512, 512%8==0, chunk 64.
  const int flat = blockIdx.y * 8 + blockIdx.x;
  const int wgid = (flat & 7) * 64 + (flat >> 3);
  const int m0   = (wgid >> 3) * 128;    // 64 m-tiles
  const int n0   = (wgid & 7) * 128;     // 8 n-tiles (innermost: A reuse)

  const int tid  = threadIdx.x;
  const int lane = tid & 63;
  const int wave = tid >> 6;
  const int l15  = lane & 15;
  const int quad = lane >> 4;
  const int sw   = l15 & 7;
  const int wm = (wave >> 1) * 64;
  const int wn = (wave & 1) * 64;

  floatx4 acc[4][4];
  for (int i = 0; i < 4; i++)
    for (int j = 0; j < 4; j++) acc[i][j] = (floatx4)0.0f;

  const int srow8 = lane >> 3;
  const int sg    = lane & 7;

  for (int kt = 0; kt < Kdim; kt += 64) {
    for (int jj = 0; jj < 4; jj++) {
      int cc = wave * 4 + jj;
      int row = cc * 8 + srow8;
      int G = sg ^ (row & 7);
      gld16(A + (size_t)(m0 + row) * Kdim + kt + G * 8, As + cc * 512);
      gld16(W + (size_t)(n0 + row) * Kdim + kt + G * 8, Bs + cc * 512);
    }
    __syncthreads();

    for (int hf = 0; hf < 2; hf++) {
      short8 af[4], bw[4];
      for (int mi = 0; mi < 4; mi++)
        af[mi] = *(const short8*)(As + (wm + mi * 16 + l15) * 64 +
                                  (((hf * 4 + quad) ^ sw) << 3));
      for (int ni = 0; ni < 4; ni++)
        bw[ni] = *(const short8*)(Bs + (wn + ni * 16 + l15) * 64 +
                                  (((hf * 4 + quad) ^ sw) << 3));
      for (int mi = 0; mi < 4; mi++)
        for (int ni = 0; ni < 4; ni++)
          acc[mi][ni] = __builtin_amdgcn_mfma_f32_16x16x32_bf16(
              bw[ni], af[mi], acc[mi][ni], 0, 0, 0);   // swapped: C^T
    }
    __syncthreads();
  }

  for (int mi = 0; mi < 4; mi++) {
    int t_abs = m0 + wm + mi * 16 + l15;
    for (int ni = 0; ni < 4; ni++) {
      int gn0 = n0 + wn + ni * 16 + quad * 4;
      floatx4 v = acc[mi][ni];
      *(float4*)(Cf + (size_t)t_abs * Ndim + gn0) = *(float4*)&v;
    }
  }
}

// ---------------------------------------------------------------- attention
// Causal flash attention, S^T formulation. One 64-row q-tile per block
// (2048 blocks, longest-first). LDS 32KB (K dbuf 16K + V single 8K + P 8K).
// V(t) staged at iter top (latency hides under QK^T+softmax); counted
// vmcnt(2) keeps K(t+1) in flight; barrier after vmcnt publishes all waves'
// V rows before PV (cross-wave publish — required, round-5 lesson).
// cvt_pk/max3 VALU diet + defer-max (T13).  (unchanged)
__launch_bounds__(256, 5)
__global__ void attn_k(const unsigned short* __restrict__ Qh,
                       const unsigned short* __restrict__ Kh,
                       const unsigned short* __restrict__ VTg,
                       unsigned short* __restrict__ Og) {
  __shared__ __align__(16) unsigned short Kt[2][64 * 64];
  __shared__ __align__(16) unsigned short Vt[64 * 64];
  __shared__ __align__(16) unsigned short Pl[64 * 64];

  const int tid  = threadIdx.x;
  const int lane = tid & 63;
  const int wave = tid >> 6;
  const int l15  = lane & 15;
  const int quad = lane >> 4;
  const int sw   = l15 & 7;
  const int bh   = blockIdx.x;
  const int a    = 31 - (int)blockIdx.y;   // longest blocks dispatch first
  const int nkt  = a + 1;

  const size_t headoff = (size_t)bh * Tseq * 64;
  const int srow8 = lane >> 3;
  const int sg    = lane & 7;
  const float kscale = 0.18033688011112042f;  // (1/8) * log2(e)
  const int b = bh >> 4, h = bh & 15;
  const int qg = a * 64 + wave * 16 + l15;    // this lane's q row

  short8 bq[2];
#pragma unroll
  for (int hf = 0; hf < 2; hf++)
    bq[hf] = *(const short8*)(Qh + headoff + (size_t)qg * 64 +
                              hf * 32 + quad * 8);

  floatx4 o[4];
#pragma unroll
  for (int nb = 0; nb < 4; nb++) o[nb] = (floatx4)0.0f;
  float mrow = -INFINITY, lrow = 0.0f;

  auto stageK = [&](int par, int kt) {
    const int k0 = kt * 64;
#pragma unroll
    for (int jj = 0; jj < 2; jj++) {
      int cc  = wave * 2 + jj;
      int row = cc * 8 + srow8;
      int G   = sg ^ (row & 7);
      gld16(Kh + headoff + (size_t)(k0 + row) * 64 + G * 8, &Kt[par][cc * 512]);
    }
  };
  auto stageV = [&](int kt) {
    const int k0 = kt * 64;
#pragma unroll
    for (int jj = 0; jj < 2; jj++) {
      int cc  = wave * 2 + jj;
      int row = cc * 8 + srow8;
      int G   = sg ^ (row & 7);
      gld16(VTg + ((size_t)bh * 64 + row) * Tseq + k0 + G * 8, Vt + cc * 512);
    }
  };

  stageK(0, 0);
  __builtin_amdgcn_sched_barrier(0);
  asm volatile("s_waitcnt vmcnt(0)");
  barrier_raw();

  for (int kt = 0; kt < nkt; kt++) {
    const int par = kt & 1;
    const int k0 = kt * 64;
    // V(t) first, then K(t+1): before PV, vmcnt(2) waits V only.
    stageV(kt);
    const bool pre = (kt + 1 < nkt);
    if (pre) stageK(par ^ 1, kt + 1);
    __builtin_amdgcn_sched_barrier(0);

    // QK^T (S^T frag: lane l15 = q-row, quad*4+r (+16nb) = k)
    floatx4 st[4];
#pragma unroll
    for (int nb = 0; nb < 4; nb++) {
      const unsigned short* kr = &Kt[par][(nb * 16 + l15) * 64];
      short8 ak0 = *(const short8*)(kr + ((quad ^ sw) << 3));
      short8 ak1 = *(const short8*)(kr + (((quad + 4) ^ sw) << 3));
      floatx4 acc0 = (floatx4)0.0f;
      acc0 = __builtin_amdgcn_mfma_f32_16x16x32_bf16(ak0, bq[0], acc0, 0, 0, 0);
      acc0 = __builtin_amdgcn_mfma_f32_16x16x32_bf16(ak1, bq[1], acc0, 0, 0, 0);
      st[nb] = acc0;
    }

    if (kt == nkt - 1) {   // only the diagonal tile needs masking
#pragma unroll
      for (int nb = 0; nb < 4; nb++)
#pragma unroll
        for (int r = 0; r < 4; r++) {
          int kg = k0 + nb * 16 + quad * 4 + r;
          if (kg > qg) st[nb][r] = -INFINITY;
        }
    }

    // row max: v_max3 tree (16 -> 8 ops) + cross-quad shfl
    float m0_ = max3f(st[0][0], st[0][1], st[0][2]);
    float m1_ = max3f(st[0][3], st[1][0], st[1][1]);
    float m2_ = max3f(st[1][2], st[1][3], st[2][0]);
    float m3_ = max3f(st[2][1], st[2][2], st[2][3]);
    float m4_ = max3f(st[3][0], st[3][1], st[3][2]);
    float mt = fmaxf(max3f(m0_, m1_, m2_), max3f(m3_, m4_, st[3][3]));
    mt = fmaxf(mt, __shfl_xor(mt, 16, 64));
    mt = fmaxf(mt, __shfl_xor(mt, 32, 64));

    // T13 defer-max: skip rescale while growth <= 8 log2-units (P <= 2^8)
    if (!__all((mt - mrow) * kscale <= 8.0f)) {
      float mnew = fmaxf(mrow, mt);
      float al = __builtin_amdgcn_exp2f((mrow - mnew) * kscale);
      mrow = mnew;
      lrow *= al;
#pragma unroll
      for (int nb = 0; nb < 4; nb++)
#pragma unroll
        for (int r = 0; r < 4; r++) o[nb][r] *= al;
    }
    const float ms = mrow * kscale;

    float rs = 0.0f;
    const int prow = (wave * 16 + l15) * 64;
#pragma unroll
    for (int nb = 0; nb < 4; nb++) {
      float p0 = __builtin_amdgcn_exp2f(__builtin_fmaf(st[nb][0], kscale, -ms));
      float p1 = __builtin_amdgcn_exp2f(__builtin_fmaf(st[nb][1], kscale, -ms));
      float p2 = __builtin_amdgcn_exp2f(__builtin_fmaf(st[nb][2], kscale, -ms));
      float p3 = __builtin_amdgcn_exp2f(__builtin_fmaf(st[nb][3], kscale, -ms));
      rs += (p0 + p1) + (p2 + p3);
      uint2 w = {cvtpk(p0, p1), cvtpk(p2, p3)};
      int klb = nb * 16 + quad * 4;
      int colp = (((klb >> 3) ^ sw) << 3) | (klb & 7);
      *(uint2*)(Pl + prow + colp) = w;
    }
    rs += __shfl_xor(rs, 16, 64);
    rs += __shfl_xor(rs, 32, 64);
    lrow += rs;

    // wait own V(t) loads (K(t+1) stays in flight), then BARRIER to publish
    // every wave's V rows before PV reads the full tile.
    __builtin_amdgcn_sched_barrier(0);
    if (pre) asm volatile("s_waitcnt vmcnt(2)");
    else     asm volatile("s_waitcnt vmcnt(0)");
    barrier_raw();

    // PV
    short8 av[4][2];
#pragma unroll
    for (int nb = 0; nb < 4; nb++) {
      const unsigned short* vr = Vt + (nb * 16 + l15) * 64;
      av[nb][0] = *(const short8*)(vr + ((quad ^ sw) << 3));
      av[nb][1] = *(const short8*)(vr + (((quad + 4) ^ sw) << 3));
    }
    const unsigned short* pr = Pl + prow;
    short8 bp0 = *(const short8*)(pr + ((quad ^ sw) << 3));
    short8 bp1 = *(const short8*)(pr + (((quad + 4) ^ sw) << 3));
#pragma unroll
    for (int nb = 0; nb < 4; nb++) {
      o[nb] = __builtin_amdgcn_mfma_f32_16x16x32_bf16(av[nb][0], bp0, o[nb], 0, 0, 0);
      o[nb] = __builtin_amdgcn_mfma_f32_16x16x32_bf16(av[nb][1], bp1, o[nb], 0, 0, 0);
    }

    // drain K(t+1) (long since issued); barrier frees Vt/Pl for next iter
    __builtin_amdgcn_sched_barrier(0);
    asm volatile("s_waitcnt vmcnt(0)");
    barrier_raw();
  }

  float inv = 1.0f / lrow;
  size_t rowoff = ((size_t)(b * Tseq + qg)) * 1024 + h * 64;
#pragma unroll
  for (int nb = 0; nb < 4; nb++) {
    ushort4 w;
    w.x = f2b(o[nb][0] * inv);
    w.y = f2b(o[nb][1] * inv);
    w.z = f2b(o[nb][2] * inv);
    w.w = f2b(o[nb][3] * inv);
    *(ushort4*)(Og + rowoff + nb * 16 + quad * 4) = w;
  }
}

// ---------------------------------------------------------------- launcher
extern "C" void kernel_launch(void* const* d_in, const int* in_sizes, int n_in,
                              void* d_out, int out_size, void* d_ws, size_t ws_size,
                              hipStream_t stream) {
  const float* q  = (const float*)d_in[0];
  const float* k  = (const float*)d_in[1];
  const float* v  = (const float*)d_in[2];
  const float* wq = (const float*)d_in[3];
  const float* wk = (const float*)d_in[4];
  const float* wv = (const float*)d_in[5];
  const float* wo = (const float*)d_in[6];
  // d_in[7] = attn_mask: deterministically causal; handled analytically.
  float* out = (float*)d_out;

  constexpr size_t BTD = (size_t)Mdim * Kdim;
  constexpr size_t DD  = (size_t)Ndim * Kdim;
  constexpr size_t MB16 = BTD * 2;

  char* ws = (char*)d_ws;
  unsigned short* Qh  = (unsigned short*)(ws);
  unsigned short* Kh  = (unsigned short*)(ws + MB16);
  unsigned short* VTg = (unsigned short*)(ws + 2 * MB16);
  unsigned short* Og  = (unsigned short*)(ws + 3 * MB16);
  unsigned short* qb  = (unsigned short*)(ws + 4 * MB16);
  unsigned short* kb  = (unsigned short*)(ws + 5 * MB16);
  unsigned short* vb  = (unsigned short*)(ws + 6 * MB16);
  unsigned short* wqb = (unsigned short*)(ws + 7 * MB16);
  unsigned short* wkb = wqb + DD;
  unsigned short* wvb = wkb + DD;
  unsigned short* wob = wvb + DD;

  float* Kout = out + BTD;
  float* Vout = out + 2 * BTD;

  cast_k<<<dim3(4096, 7), 256, 0, stream>>>(q, k, v, wq, wk, wv, wo,
                                            qb, kb, vb, wqb, wkb, wvb, wob);

  gemm_qkv<<<dim3(8, 64, 3), 256, 0, stream>>>(
      qb, kb, vb, wqb, wkb, wvb, Qh, Kh, Kout, VTg, Vout);

  attn_k<<<dim3(4 * NH, 32), 256, 0, stream>>>(Qh, Kh, VTg, Og);

  gemm_o<<<dim3(8, 64), 256, 0, stream>>>(Og, wob, out);
}